// Round 8
// baseline (1851.866 us; speedup 1.0000x reference)
//
#include <hip/hip_runtime.h>
#include <math.h>

#define D 256
#define PD 260  // padded LDS row: %4==0 (float4-aligned), %32==4 (bank shift)
#define TOK_B 16
#define TOK_T 8192
#define NTOK (TOK_B * TOK_T)
#define KSEL 100
#define ROWS 128  // R15: 128 tokens/block, 16 rows/thread, 1 block/CU (ILP bet)

typedef unsigned long long ull;

// ---- scratch in device globals (d_ws untouched) ----
__device__ float g_txt[TOK_B * D];   // normalized text (f32, np semantics)
__device__ float g_obj[NTOK];        // obj sigmoid scores (f32)
__device__ int   g_sel[TOK_B * KSEL];

// ---------------------------------------------------------------------------
// numpy pairwise_sum emulation (serial form, used by K0).
// ---------------------------------------------------------------------------
template <typename F>
__device__ __forceinline__ float np_sum128_f(F f, int base) {
#pragma clang fp contract(off)
  float r0 = f(base + 0), r1 = f(base + 1), r2 = f(base + 2), r3 = f(base + 3);
  float r4 = f(base + 4), r5 = f(base + 5), r6 = f(base + 6), r7 = f(base + 7);
  for (int i = 8; i < 128; i += 8) {
    r0 += f(base + i + 0); r1 += f(base + i + 1);
    r2 += f(base + i + 2); r3 += f(base + i + 3);
    r4 += f(base + i + 4); r5 += f(base + i + 5);
    r6 += f(base + i + 6); r7 += f(base + i + 7);
  }
  return ((r0 + r1) + (r2 + r3)) + ((r4 + r5) + (r6 + r7));
}
template <typename F>
__device__ __forceinline__ float np_sum256_f(F f) {
#pragma clang fp contract(off)
  return np_sum128_f(f, 0) + np_sum128_f(f, 128);
}

// ---------------------------------------------------------------------------
// Parallel np pairwise sum: 8 lanes (j = lane&7) compute numpy accumulator
// r_j of both 128-halves in np order; combine tree via shfl_xor is
// bit-identical to np's ((r0+r1)+(r2+r3))+((r4+r5)+(r6+r7)).
// ---------------------------------------------------------------------------
template <typename F>
__device__ __forceinline__ float np_sum256_par8(F f, int j) {
#pragma clang fp contract(off)
  float s0 = f(j);
  for (int i = 1; i < 16; ++i) s0 += f(8 * i + j);
  float s1 = f(128 + j);
  for (int i = 1; i < 16; ++i) s1 += f(128 + 8 * i + j);
  s0 += __shfl_xor(s0, 1);
  s0 += __shfl_xor(s0, 2);
  s0 += __shfl_xor(s0, 4);
  s1 += __shfl_xor(s1, 1);
  s1 += __shfl_xor(s1, 2);
  s1 += __shfl_xor(s1, 4);
  return s0 + s1;
}

// scipy-style gelu: f32 divide by f32(sqrt2), f64 erf, f32 compose
__device__ __forceinline__ float np_geluf(float x) {
#pragma clang fp contract(off)
  const float t = x / 1.41421356237309504880f;
  const float e = (float)erf((double)t);
  return (0.5f * x) * (1.0f + e);
}
__device__ __forceinline__ float np_sigmoidf(float x) {
#pragma clang fp contract(off)
  return 1.0f / (1.0f + expf(-x));
}

// ---------------------------------------------------------------------------
// K0: txt = text_emb / sqrt(np.sum(text^2) + 1e-12), all f32 np semantics.
// ---------------------------------------------------------------------------
__global__ __launch_bounds__(256) void k0_txt(const float* __restrict__ text_emb) {
#pragma clang fp contract(off)
  const int b = blockIdx.x, tid = threadIdx.x;
  __shared__ float sSq[D];
  __shared__ float sTot;
  const float e = text_emb[b * D + tid];
  sSq[tid] = e * e;
  __syncthreads();
  if (tid == 0) {
    const float* p = sSq;
    sTot = np_sum256_f([&](int i) { return p[i]; });
  }
  __syncthreads();
  g_txt[b * D + tid] = e / sqrtf(sTot + 1e-12f);
}

// ---------------------------------------------------------------------------
// accumulating GEMM microkernel, R15: 16-row variant of the R6/R13-proven
// simple form (no pipelining, no sched pragmas, no LDS-W — direct L2 W
// reads + broadcast A from LDS won on 3 rounds of evidence).
// acc[16][8] += S[r0..r0+15][:] @ W[:,c0..c0+7], strictly ascending k, one
// f32 fma chain per C element (bit-exact vs np). Per 4-k group: 16 LDS
// broadcast reads + 8 global W loads + 512 FMA wave-instrs (1024 cy) —
// exposed W latency amortizes to ~20%.
// ---------------------------------------------------------------------------
__device__ __forceinline__ void gemm_acc16(const float (*__restrict__ S)[PD],
                                           const float* __restrict__ W, int r0,
                                           int c0, float acc[16][8]) {
  for (int k = 0; k < D; k += 4) {
    float ar[16][4];
#pragma unroll
    for (int i = 0; i < 16; ++i) {
      const float4 A = *(const float4*)&S[r0 + i][k];
      ar[i][0] = A.x; ar[i][1] = A.y; ar[i][2] = A.z; ar[i][3] = A.w;
    }
#pragma unroll
    for (int kk = 0; kk < 4; ++kk) {
      const float* wr = W + (size_t)(k + kk) * D + c0;
      float4 W0 = *(const float4*)wr;
      float4 W1 = *(const float4*)(wr + 4);
      const float wv[8] = {W0.x, W0.y, W0.z, W0.w, W1.x, W1.y, W1.z, W1.w};
#pragma unroll
      for (int i = 0; i < 16; ++i)
#pragma unroll
        for (int j = 0; j < 8; ++j)
          acc[i][j] = fmaf(ar[i][kk], wv[j], acc[i][j]);
    }
  }
}

// ---------------------------------------------------------------------------
// K1: obj scores for all tokens, bit-exact np-f32 semantics.
// R15: 128 tokens/block, 16 rows x 8 cols per thread. W traffic = waves x
// full-panel, so halving waves again (vs R13) halves the dominant operand
// stream (8.6 -> 4.3 GB); per-group compute 1024 cy per 8 W loads makes
// even fully-exposed L2 latency ~20%. LDS ~136 KB -> 1 block/CU (1 wave/
// SIMD — pure ILP). VGPR ~184 of 512 budget at bounds(256,1): no spill.
// Per-output arithmetic identical to R6-R13 (ascending-k single fma chain).
// ---------------------------------------------------------------------------
__global__ __launch_bounds__(256, 1) void k1_obj(
    const float* __restrict__ vision, const float* __restrict__ fuse_w1,
    const float* __restrict__ fuse_b1, const float* __restrict__ fuse_w2,
    const float* __restrict__ fuse_b2, const float* __restrict__ obj_ln_g,
    const float* __restrict__ obj_ln_b, const float* __restrict__ obj_w1,
    const float* __restrict__ obj_b1, const float* __restrict__ obj_w2,
    const float* __restrict__ obj_b2) {
#pragma clang fp contract(off)
  const int tid = threadIdx.x;
  const int tr = tid >> 5, tc = tid & 31;
  const int r0 = tr << 4, c0 = tc << 3;   // 16 rows x 8 cols per thread
  const int blk = blockIdx.x;
  const int batch = blk >> 6;  // 64 blocks per batch (8192 tokens / 128)

  __shared__ float sA[ROWS][PD];  // vision -> gelu1 -> h -> oh -> q (in-place)
  __shared__ float sTxt[D];
  __shared__ float sMu[ROWS], sRstd[ROWS];

  // stage vision tile + txt row (pad-aware)
  {
    const float* src = vision + (size_t)blk * (ROWS * D);
#pragma unroll
    for (int i = 0; i < 32; ++i) {
      const int e = i * 1024 + tid * 4;
      const int row = e >> 8, col = e & 255;
      *(float4*)&sA[row][col] = *(const float4*)(src + e);
    }
    sTxt[tid] = g_txt[batch * D + tid];
  }
  __syncthreads();

  float acc[16][8];
#pragma unroll
  for (int i = 0; i < 16; ++i)
#pragma unroll
    for (int j = 0; j < 8; ++j) acc[i][j] = 0.0f;

  // GEMM1 part A: vision rows, k = 0..255 (ascending)
  gemm_acc16(sA, fuse_w1, r0, c0, acc);
  // GEMM1 part B: text rows, k = 256..511 (ascending); tv broadcast per k
  for (int k = 0; k < D; ++k) {
    const float tv = sTxt[k];
    const float* wr = fuse_w1 + (size_t)(D + k) * D + c0;
    float4 W0 = *(const float4*)wr;
    float4 W1 = *(const float4*)(wr + 4);
    const float wv[8] = {W0.x, W0.y, W0.z, W0.w, W1.x, W1.y, W1.z, W1.w};
#pragma unroll
    for (int i = 0; i < 16; ++i)
#pragma unroll
      for (int j = 0; j < 8; ++j) acc[i][j] = fmaf(tv, wv[j], acc[i][j]);
  }
  __syncthreads();  // all GEMM1 reads of sA (vision) complete
  // + b1, gelu -> sA (in place)
  {
#pragma unroll
    for (int j2 = 0; j2 < 8; ++j2) {
      const float b = fuse_b1[c0 + j2];
#pragma unroll
      for (int i = 0; i < 16; ++i)
        sA[r0 + i][c0 + j2] = np_geluf(acc[i][j2] + b);
    }
  }
  __syncthreads();

  // GEMM2: h = gelu1 @ w2 + b2 -> sA (in place)
#pragma unroll
  for (int i = 0; i < 16; ++i)
#pragma unroll
    for (int j = 0; j < 8; ++j) acc[i][j] = 0.0f;
  gemm_acc16(sA, fuse_w2, r0, c0, acc);
  __syncthreads();  // all GEMM2 reads of sA (gelu1) complete
  {
#pragma unroll
    for (int j2 = 0; j2 < 8; ++j2) {
      const float b = fuse_b2[c0 + j2];
#pragma unroll
      for (int i = 0; i < 16; ++i) sA[r0 + i][c0 + j2] = acc[i][j2] + b;
    }
  }
  __syncthreads();

  // LN stats, numpy pairwise, 8 lanes per row (exact np order); rows 0..127
  {
    const int j = tid & 7;
    for (int r = tid >> 3; r < ROWS; r += 32) {
      const float* hrow = &sA[r][0];
      const float mu =
          np_sum256_par8([&](int i) { return hrow[i]; }, j) / 256.0f;
      const float var = np_sum256_par8(
                            [&](int i) {
                              const float d = hrow[i] - mu;
                              return d * d;
                            },
                            j) /
                        256.0f;
      if (j == 0) {
        sMu[r] = mu;
        sRstd[r] = 1.0f / sqrtf(var + 1e-5f);
      }
    }
  }
  __syncthreads();

  // oh = ((h-mu)*rstd)*g + b -> sA (column-parallel, each thread owns col tid)
  {
    const float lg = obj_ln_g[tid], lb = obj_ln_b[tid];
    for (int r = 0; r < ROWS; ++r) {
      const float t = (sA[r][tid] - sMu[r]) * sRstd[r];
      sA[r][tid] = t * lg + lb;
    }
  }
  __syncthreads();

  // obj head GEMM: q = gelu(oh @ ow1 + ob1) -> sA (in place)
#pragma unroll
  for (int i = 0; i < 16; ++i)
#pragma unroll
    for (int j = 0; j < 8; ++j) acc[i][j] = 0.0f;
  gemm_acc16(sA, obj_w1, r0, c0, acc);
  __syncthreads();  // all obj-GEMM reads of sA (oh) complete
  {
#pragma unroll
    for (int j2 = 0; j2 < 8; ++j2) {
      const float b = obj_b1[c0 + j2];
#pragma unroll
      for (int i = 0; i < 16; ++i)
        sA[r0 + i][c0 + j2] = np_geluf(acc[i][j2] + b);
    }
  }
  __syncthreads();

  // logit = (q . ow2) + ob2, sequential ascending fma (np semantics).
  if (tid < ROWS) {
    const int row = tid;
    const float* q = &sA[row][0];
    float L = 0.0f;
    for (int k = 0; k < D; ++k) L = fmaf(q[k], obj_w2[k], L);
    L = L + obj_b2[0];
    g_obj[(size_t)blk * ROWS + row] = np_sigmoidf(L);
  }
}

// ---------------------------------------------------------------------------
// K2: per-batch top-100 via 128-group max tournament. Group g = elements
// {g + 128*j}; init reads are lane-consecutive (conflict-free). Per round:
// wave0 scans 128 group maxima, extracts winner (np tie semantics via packed
// key), zeroes it, recomputes only the winner's group.
// ---------------------------------------------------------------------------
__global__ __launch_bounds__(256) void k2_topk(float* __restrict__ out_scores) {
  const int b = blockIdx.x, tid = threadIdx.x;
  __shared__ ull sKey[TOK_T];
  __shared__ ull sGmax[128];
  __shared__ int sWin;
  for (int i = tid; i < TOK_T; i += 256) {
    const float s = g_obj[b * TOK_T + i];
    sKey[i] = ((ull)__float_as_uint(s) << 32) | (unsigned)(TOK_T - 1 - i);
  }
  __syncthreads();
  // init group maxima: thread t<128 scans its strided group (lane-consecutive)
  if (tid < 128) {
    ull m = 0ull;
    for (int j = 0; j < 64; ++j) {
      const ull v = sKey[tid + 128 * j];
      m = v > m ? v : m;
    }
    sGmax[tid] = m;
  }
  __syncthreads();
  for (int r = 0; r < KSEL; ++r) {
    if (tid < 64) {
      ull m = sGmax[tid];
      const ull o = sGmax[64 + tid];
      if (o > m) m = o;
#pragma unroll
      for (int off = 32; off > 0; off >>= 1) {
        const ull o2 = __shfl_down(m, off, 64);
        if (o2 > m) m = o2;
      }
      if (tid == 0) {
        const int idx = (TOK_T - 1) - (int)(unsigned)(m & 0xFFFFFFFFull);
        out_scores[b * KSEL + r] = __uint_as_float((unsigned)(m >> 32));
        g_sel[b * KSEL + r] = idx;
        sKey[idx] = 0ull;
        sWin = idx & 127;
      }
    }
    __syncthreads();
    if (tid < 64) {
      const int g = sWin;
      ull v = sKey[g + 128 * tid];
#pragma unroll
      for (int off = 32; off > 0; off >>= 1) {
        const ull o = __shfl_down(v, off, 64);
        if (o > v) v = o;
      }
      if (tid == 0) sGmax[g] = v;
    }
    __syncthreads();
  }
}

// ---------------------------------------------------------------------------
// K3: box head + text scores for the 1600 selected tokens, np-f32 semantics.
// 8 tokens/block, 256 threads (thread = output column); stats 8 lanes/row.
// ---------------------------------------------------------------------------
__global__ __launch_bounds__(256) void k3_box(
    const float* __restrict__ vision, const float* __restrict__ fuse_w1,
    const float* __restrict__ fuse_b1, const float* __restrict__ fuse_w2,
    const float* __restrict__ fuse_b2, const float* __restrict__ box_ln_g,
    const float* __restrict__ box_ln_b, const float* __restrict__ box_w1,
    const float* __restrict__ box_b1, const float* __restrict__ box_w2,
    const float* __restrict__ box_b2, float* __restrict__ out) {
#pragma clang fp contract(off)
  const int tid = threadIdx.x, c = tid;
  __shared__ float sV[8][PD];    // vision -> q(box)
  __shared__ float sG[8][PD];    // gelu1 -> bh
  __shared__ float sH[8][PD];    // h
  __shared__ float sTx[8][PD];   // per-token txt row
  __shared__ float sMu[8], sRstd[8];
  __shared__ int sIdx[8], sBat[8];
  if (tid < 8) {
    const int e = blockIdx.x * 8 + tid;
    sBat[tid] = e / KSEL;
    sIdx[tid] = g_sel[e];
  }
  __syncthreads();
  {
    const int u = tid >> 5, col = (tid & 31) * 8;
    const float* src = vision + ((size_t)sBat[u] * TOK_T + sIdx[u]) * D + col;
    *(float4*)&sV[u][col] = *(const float4*)src;
    *(float4*)&sV[u][col + 4] = *(const float4*)(src + 4);
    const float* tsrc = &g_txt[sBat[u] * D + col];
    *(float4*)&sTx[u][col] = *(const float4*)tsrc;
    *(float4*)&sTx[u][col + 4] = *(const float4*)(tsrc + 4);
  }
  __syncthreads();

  float acc[8];
#pragma unroll
  for (int u = 0; u < 8; ++u) acc[u] = 0.0f;
  // GEMM1: k = 0..255 vision, then k = 256..511 text (ascending)
  for (int k = 0; k < D; ++k) {
    const float w = fuse_w1[k * D + c];
#pragma unroll
    for (int u = 0; u < 8; ++u) acc[u] = fmaf(sV[u][k], w, acc[u]);
  }
  for (int k = 0; k < D; ++k) {
    const float w = fuse_w1[(D + k) * D + c];
#pragma unroll
    for (int u = 0; u < 8; ++u) acc[u] = fmaf(sTx[u][k], w, acc[u]);
  }
  {
    const float b = fuse_b1[c];
#pragma unroll
    for (int u = 0; u < 8; ++u) sG[u][c] = np_geluf(acc[u] + b);
  }
  __syncthreads();

  // GEMM2 -> h
#pragma unroll
  for (int u = 0; u < 8; ++u) acc[u] = 0.0f;
  for (int k = 0; k < D; ++k) {
    const float w = fuse_w2[k * D + c];
#pragma unroll
    for (int u = 0; u < 8; ++u) acc[u] = fmaf(sG[u][k], w, acc[u]);
  }
  {
    const float b = fuse_b2[c];
#pragma unroll
    for (int u = 0; u < 8; ++u) sH[u][c] = acc[u] + b;
  }
  __syncthreads();

  // per-token stats (np pairwise), 8 lanes per row; rows 0..7 on wave 0/1
  {
    const int u = tid >> 3, j = tid & 7;
    if (u < 8) {
      const float* h = &sH[u][0];
      const float* tx = &sTx[u][0];
      const float mu = np_sum256_par8([&](int i) { return h[i]; }, j) / 256.0f;
      const float var = np_sum256_par8(
                            [&](int i) {
                              const float d = h[i] - mu;
                              return d * d;
                            },
                            j) /
                        256.0f;
      const float q2 = np_sum256_par8([&](int i) { return h[i] * h[i]; }, j);
      const float den = sqrtf(q2 + 1e-12f);
      const float ts =
          np_sum256_par8([&](int i) { return (h[i] / den) * tx[i]; }, j);
      if (j == 0) {
        sMu[u] = mu;
        sRstd[u] = 1.0f / sqrtf(var + 1e-5f);
        out[8000 + blockIdx.x * 8 + u] = ts;
      }
    }
  }
  __syncthreads();

  // bh -> sG
  {
    const float lg = box_ln_g[c], lb = box_ln_b[c];
#pragma unroll
    for (int u = 0; u < 8; ++u) {
      const float t = (sH[u][c] - sMu[u]) * sRstd[u];
      sG[u][c] = t * lg + lb;
    }
  }
  __syncthreads();

  // box GEMM: q = gelu(bh @ bw1 + bb1) -> sV
#pragma unroll
  for (int u = 0; u < 8; ++u) acc[u] = 0.0f;
  for (int k = 0; k < D; ++k) {
    const float w = box_w1[k * D + c];
#pragma unroll
    for (int u = 0; u < 8; ++u) acc[u] = fmaf(sG[u][k], w, acc[u]);
  }
  {
    const float b = box_b1[c];
#pragma unroll
    for (int u = 0; u < 8; ++u) sV[u][c] = np_geluf(acc[u] + b);
  }
  __syncthreads();

  // logits: sequential ascending fma per (token, j), then + b2, sigmoid
  if (tid < 32) {
    const int u = tid >> 2, j = tid & 3;
    const float* q = &sV[u][0];
    float L = 0.0f;
    for (int k = 0; k < D; ++k) L = fmaf(q[k], box_w2[k * 4 + j], L);
    L = L + box_b2[j];
    out[(blockIdx.x * 8 + u) * 4 + j] = np_sigmoidf(L);
  }
}

extern "C" void kernel_launch(void* const* d_in, const int* in_sizes, int n_in,
                              void* d_out, int out_size, void* d_ws,
                              size_t ws_size, hipStream_t stream) {
  const float* vision   = (const float*)d_in[0];
  const float* text_emb = (const float*)d_in[1];
  const float* fuse_w1  = (const float*)d_in[2];
  const float* fuse_b1  = (const float*)d_in[3];
  const float* fuse_w2  = (const float*)d_in[4];
  const float* fuse_b2  = (const float*)d_in[5];
  const float* box_ln_g = (const float*)d_in[6];
  const float* box_ln_b = (const float*)d_in[7];
  const float* box_w1   = (const float*)d_in[8];
  const float* box_b1   = (const float*)d_in[9];
  const float* box_w2   = (const float*)d_in[10];
  const float* box_b2   = (const float*)d_in[11];
  const float* obj_ln_g = (const float*)d_in[12];
  const float* obj_ln_b = (const float*)d_in[13];
  const float* obj_w1   = (const float*)d_in[14];
  const float* obj_b1   = (const float*)d_in[15];
  const float* obj_w2   = (const float*)d_in[16];
  const float* obj_b2   = (const float*)d_in[17];
  float* out = (float*)d_out;

  k0_txt<<<TOK_B, 256, 0, stream>>>(text_emb);
  k1_obj<<<NTOK / ROWS, 256, 0, stream>>>(
      vision, fuse_w1, fuse_b1, fuse_w2, fuse_b2, obj_ln_g, obj_ln_b, obj_w1,
      obj_b1, obj_w2, obj_b2);
  k2_topk<<<TOK_B, 256, 0, stream>>>(out + 6400);
  k3_box<<<(TOK_B * KSEL) / 8, 256, 0, stream>>>(
      vision, fuse_w1, fuse_b1, fuse_w2, fuse_b2, box_ln_g, box_ln_b, box_w1,
      box_b1, box_w2, box_b2, out);
}

// Round 9
// 1430.258 us; speedup vs baseline: 1.2948x; 1.2948x over previous
//
#include <hip/hip_runtime.h>
#include <math.h>

#define D 256
#define PD 260  // padded LDS row: %4==0 (float4-aligned), %32==4 (bank shift)
#define TOK_B 16
#define TOK_T 8192
#define NTOK (TOK_B * TOK_T)
#define KSEL 100
#define ROWS 64  // R13 optimum: 64 tokens/block, 8 rows/thread, 2 blocks/CU

typedef unsigned long long ull;

// ---- scratch in device globals (d_ws untouched) ----
__device__ float g_txt[TOK_B * D];   // normalized text (f32, np semantics)
__device__ float g_obj[NTOK];        // obj sigmoid scores (f32)
__device__ int   g_sel[TOK_B * KSEL];

// ---------------------------------------------------------------------------
// numpy pairwise_sum emulation (serial form, used by K0).
// ---------------------------------------------------------------------------
template <typename F>
__device__ __forceinline__ float np_sum128_f(F f, int base) {
#pragma clang fp contract(off)
  float r0 = f(base + 0), r1 = f(base + 1), r2 = f(base + 2), r3 = f(base + 3);
  float r4 = f(base + 4), r5 = f(base + 5), r6 = f(base + 6), r7 = f(base + 7);
  for (int i = 8; i < 128; i += 8) {
    r0 += f(base + i + 0); r1 += f(base + i + 1);
    r2 += f(base + i + 2); r3 += f(base + i + 3);
    r4 += f(base + i + 4); r5 += f(base + i + 5);
    r6 += f(base + i + 6); r7 += f(base + i + 7);
  }
  return ((r0 + r1) + (r2 + r3)) + ((r4 + r5) + (r6 + r7));
}
template <typename F>
__device__ __forceinline__ float np_sum256_f(F f) {
#pragma clang fp contract(off)
  return np_sum128_f(f, 0) + np_sum128_f(f, 128);
}

// ---------------------------------------------------------------------------
// Parallel np pairwise sum: 8 lanes (j = lane&7) compute numpy accumulator
// r_j of both 128-halves in np order; combine tree via shfl_xor is
// bit-identical to np's ((r0+r1)+(r2+r3))+((r4+r5)+(r6+r7)).
// ---------------------------------------------------------------------------
template <typename F>
__device__ __forceinline__ float np_sum256_par8(F f, int j) {
#pragma clang fp contract(off)
  float s0 = f(j);
  for (int i = 1; i < 16; ++i) s0 += f(8 * i + j);
  float s1 = f(128 + j);
  for (int i = 1; i < 16; ++i) s1 += f(128 + 8 * i + j);
  s0 += __shfl_xor(s0, 1);
  s0 += __shfl_xor(s0, 2);
  s0 += __shfl_xor(s0, 4);
  s1 += __shfl_xor(s1, 1);
  s1 += __shfl_xor(s1, 2);
  s1 += __shfl_xor(s1, 4);
  return s0 + s1;
}

// scipy-style gelu: f32 divide by f32(sqrt2), f64 erf, f32 compose
__device__ __forceinline__ float np_geluf(float x) {
#pragma clang fp contract(off)
  const float t = x / 1.41421356237309504880f;
  const float e = (float)erf((double)t);
  return (0.5f * x) * (1.0f + e);
}
__device__ __forceinline__ float np_sigmoidf(float x) {
#pragma clang fp contract(off)
  return 1.0f / (1.0f + expf(-x));
}

// ---------------------------------------------------------------------------
// K0: txt = text_emb / sqrt(np.sum(text^2) + 1e-12), all f32 np semantics.
// ---------------------------------------------------------------------------
__global__ __launch_bounds__(256) void k0_txt(const float* __restrict__ text_emb) {
#pragma clang fp contract(off)
  const int b = blockIdx.x, tid = threadIdx.x;
  __shared__ float sSq[D];
  __shared__ float sTot;
  const float e = text_emb[b * D + tid];
  sSq[tid] = e * e;
  __syncthreads();
  if (tid == 0) {
    const float* p = sSq;
    sTot = np_sum256_f([&](int i) { return p[i]; });
  }
  __syncthreads();
  g_txt[b * D + tid] = e / sqrtf(sTot + 1e-12f);
}

// ---------------------------------------------------------------------------
// R16 GEMM: R13's proven 8x8 tile + W register double-bank prefetch PINNED
// with sched_barrier(0). Per 8-k iteration:
//   [load bankY <- rows k+4..k+7] |SB| [FMA bankX @ k, 512 cy]
//   [load bankX <- rows k+8..k+11] |SB| [FMA bankY @ k+4]
// Load->use distance = one full FMA half (512 cy) -> L1/L2 latency covered.
// R4's spill lesson: pins are safe ONLY with VGPR headroom — here
// bounds(256,2) gives a 256-reg budget, est. liveness ~185.
// Prefetch row base wraps &(D-1): dead loads, always in-bounds.
// FMA chain per C element strictly ascending k — bit-exact vs R13/R6.
// ---------------------------------------------------------------------------
__device__ __forceinline__ void gemm_acc8(const float (*__restrict__ S)[PD],
                                          const float* __restrict__ W, int r0,
                                          int c0, float acc[8][8]) {
  const float* __restrict__ wb = W + c0;
  float4 X0, X1, X2, X3, X4, X5, X6, X7;  // bank X: 4 W rows (2 float4 each)
  float4 Y0, Y1, Y2, Y3, Y4, Y5, Y6, Y7;  // bank Y
  X0 = *(const float4*)(wb + 0 * D);
  X1 = *(const float4*)(wb + 0 * D + 4);
  X2 = *(const float4*)(wb + 1 * D);
  X3 = *(const float4*)(wb + 1 * D + 4);
  X4 = *(const float4*)(wb + 2 * D);
  X5 = *(const float4*)(wb + 2 * D + 4);
  X6 = *(const float4*)(wb + 3 * D);
  X7 = *(const float4*)(wb + 3 * D + 4);

#define LOAD_BANK(B0, B1, B2, B3, B4, B5, B6, B7, ROWBASE)                   \
  {                                                                          \
    const float* wn_ = wb + (size_t)(ROWBASE) * D;                           \
    B0 = *(const float4*)(wn_ + 0 * D);                                      \
    B1 = *(const float4*)(wn_ + 0 * D + 4);                                  \
    B2 = *(const float4*)(wn_ + 1 * D);                                      \
    B3 = *(const float4*)(wn_ + 1 * D + 4);                                  \
    B4 = *(const float4*)(wn_ + 2 * D);                                      \
    B5 = *(const float4*)(wn_ + 2 * D + 4);                                  \
    B6 = *(const float4*)(wn_ + 3 * D);                                      \
    B7 = *(const float4*)(wn_ + 3 * D + 4);                                  \
  }

#define FMA_HALF(KB, P0, P1, P2, P3, P4, P5, P6, P7)                         \
  {                                                                          \
    float ar[8][4];                                                          \
    _Pragma("unroll") for (int i = 0; i < 8; ++i) {                          \
      const float4 A = *(const float4*)&S[r0 + i][(KB)];                     \
      ar[i][0] = A.x; ar[i][1] = A.y; ar[i][2] = A.z; ar[i][3] = A.w;        \
    }                                                                        \
    const float4 wq[4][2] = {{P0, P1}, {P2, P3}, {P4, P5}, {P6, P7}};        \
    _Pragma("unroll") for (int kk = 0; kk < 4; ++kk) {                       \
      const float wv[8] = {wq[kk][0].x, wq[kk][0].y, wq[kk][0].z,            \
                           wq[kk][0].w, wq[kk][1].x, wq[kk][1].y,            \
                           wq[kk][1].z, wq[kk][1].w};                        \
      _Pragma("unroll") for (int i = 0; i < 8; ++i)                          \
        _Pragma("unroll") for (int j = 0; j < 8; ++j)                        \
          acc[i][j] = fmaf(ar[i][kk], wv[j], acc[i][j]);                     \
    }                                                                        \
  }

#pragma unroll 1
  for (int k = 0; k < D; k += 8) {
    LOAD_BANK(Y0, Y1, Y2, Y3, Y4, Y5, Y6, Y7, (k + 4) & (D - 1));
    __builtin_amdgcn_sched_barrier(0);
    FMA_HALF(k, X0, X1, X2, X3, X4, X5, X6, X7);
    LOAD_BANK(X0, X1, X2, X3, X4, X5, X6, X7, (k + 8) & (D - 1));
    __builtin_amdgcn_sched_barrier(0);
    FMA_HALF(k + 4, Y0, Y1, Y2, Y3, Y4, Y5, Y6, Y7);
  }
#undef FMA_HALF
#undef LOAD_BANK
}

// ---------------------------------------------------------------------------
// K1: obj scores for all tokens, bit-exact np-f32 semantics.
// R16 = R13 geometry (64 tokens/block, 8x8/thread, 2 blocks/CU) + pinned
// W double-bank prefetch in all three GEMMs incl. text half.
// ---------------------------------------------------------------------------
__global__ __launch_bounds__(256, 2) void k1_obj(
    const float* __restrict__ vision, const float* __restrict__ fuse_w1,
    const float* __restrict__ fuse_b1, const float* __restrict__ fuse_w2,
    const float* __restrict__ fuse_b2, const float* __restrict__ obj_ln_g,
    const float* __restrict__ obj_ln_b, const float* __restrict__ obj_w1,
    const float* __restrict__ obj_b1, const float* __restrict__ obj_w2,
    const float* __restrict__ obj_b2) {
#pragma clang fp contract(off)
  const int tid = threadIdx.x;
  const int tr = tid >> 5, tc = tid & 31;
  const int r0 = tr << 3, c0 = tc << 3;   // 8 rows x 8 cols per thread
  const int blk = blockIdx.x;
  const int batch = blk >> 7;  // 128 blocks per batch (8192 tokens / 64)

  __shared__ float sA[ROWS][PD];  // vision -> gelu1 -> h -> oh -> q (in-place)
  __shared__ float sTxt[D];
  __shared__ float sMu[ROWS], sRstd[ROWS];

  // stage vision tile + txt row (pad-aware)
  {
    const float* src = vision + (size_t)blk * (ROWS * D);
#pragma unroll
    for (int i = 0; i < 16; ++i) {
      const int e = i * 1024 + tid * 4;
      const int row = e >> 8, col = e & 255;
      *(float4*)&sA[row][col] = *(const float4*)(src + e);
    }
    sTxt[tid] = g_txt[batch * D + tid];
  }
  __syncthreads();

  float acc[8][8];
#pragma unroll
  for (int i = 0; i < 8; ++i)
#pragma unroll
    for (int j = 0; j < 8; ++j) acc[i][j] = 0.0f;

  // GEMM1 part A: vision rows, k = 0..255 (ascending)
  gemm_acc8(sA, fuse_w1, r0, c0, acc);

  // GEMM1 part B: text rows, k = 256..511 (ascending), same pinned structure
  {
    const float* __restrict__ wb = fuse_w1 + (size_t)D * D + c0;
    float4 X0, X1, X2, X3, X4, X5, X6, X7;
    float4 Y0, Y1, Y2, Y3, Y4, Y5, Y6, Y7;
    X0 = *(const float4*)(wb + 0 * D);
    X1 = *(const float4*)(wb + 0 * D + 4);
    X2 = *(const float4*)(wb + 1 * D);
    X3 = *(const float4*)(wb + 1 * D + 4);
    X4 = *(const float4*)(wb + 2 * D);
    X5 = *(const float4*)(wb + 2 * D + 4);
    X6 = *(const float4*)(wb + 3 * D);
    X7 = *(const float4*)(wb + 3 * D + 4);

#define LOAD_BANK(B0, B1, B2, B3, B4, B5, B6, B7, ROWBASE)                   \
    {                                                                        \
      const float* wn_ = wb + (size_t)(ROWBASE) * D;                         \
      B0 = *(const float4*)(wn_ + 0 * D);                                    \
      B1 = *(const float4*)(wn_ + 0 * D + 4);                                \
      B2 = *(const float4*)(wn_ + 1 * D);                                    \
      B3 = *(const float4*)(wn_ + 1 * D + 4);                                \
      B4 = *(const float4*)(wn_ + 2 * D);                                    \
      B5 = *(const float4*)(wn_ + 2 * D + 4);                                \
      B6 = *(const float4*)(wn_ + 3 * D);                                    \
      B7 = *(const float4*)(wn_ + 3 * D + 4);                                \
    }

#define FMA_TXT_HALF(KB, P0, P1, P2, P3, P4, P5, P6, P7)                     \
    {                                                                        \
      const float tv[4] = {sTxt[(KB) + 0], sTxt[(KB) + 1], sTxt[(KB) + 2],   \
                           sTxt[(KB) + 3]};                                  \
      const float4 wq[4][2] = {{P0, P1}, {P2, P3}, {P4, P5}, {P6, P7}};      \
      _Pragma("unroll") for (int kk = 0; kk < 4; ++kk) {                     \
        const float wv[8] = {wq[kk][0].x, wq[kk][0].y, wq[kk][0].z,          \
                             wq[kk][0].w, wq[kk][1].x, wq[kk][1].y,          \
                             wq[kk][1].z, wq[kk][1].w};                      \
        _Pragma("unroll") for (int i = 0; i < 8; ++i)                        \
          _Pragma("unroll") for (int j = 0; j < 8; ++j)                      \
            acc[i][j] = fmaf(tv[kk], wv[j], acc[i][j]);                      \
      }                                                                      \
    }

#pragma unroll 1
    for (int k = 0; k < D; k += 8) {
      LOAD_BANK(Y0, Y1, Y2, Y3, Y4, Y5, Y6, Y7, (k + 4) & (D - 1));
      __builtin_amdgcn_sched_barrier(0);
      FMA_TXT_HALF(k, X0, X1, X2, X3, X4, X5, X6, X7);
      LOAD_BANK(X0, X1, X2, X3, X4, X5, X6, X7, (k + 8) & (D - 1));
      __builtin_amdgcn_sched_barrier(0);
      FMA_TXT_HALF(k + 4, Y0, Y1, Y2, Y3, Y4, Y5, Y6, Y7);
    }
#undef FMA_TXT_HALF
#undef LOAD_BANK
  }
  __syncthreads();  // all GEMM1 reads of sA (vision) complete
  // + b1, gelu -> sA (in place)
  {
#pragma unroll
    for (int j2 = 0; j2 < 8; ++j2) {
      const float b = fuse_b1[c0 + j2];
#pragma unroll
      for (int i = 0; i < 8; ++i)
        sA[r0 + i][c0 + j2] = np_geluf(acc[i][j2] + b);
    }
  }
  __syncthreads();

  // GEMM2: h = gelu1 @ w2 + b2 -> sA (in place)
#pragma unroll
  for (int i = 0; i < 8; ++i)
#pragma unroll
    for (int j = 0; j < 8; ++j) acc[i][j] = 0.0f;
  gemm_acc8(sA, fuse_w2, r0, c0, acc);
  __syncthreads();  // all GEMM2 reads of sA (gelu1) complete
  {
#pragma unroll
    for (int j2 = 0; j2 < 8; ++j2) {
      const float b = fuse_b2[c0 + j2];
#pragma unroll
      for (int i = 0; i < 8; ++i) sA[r0 + i][c0 + j2] = acc[i][j2] + b;
    }
  }
  __syncthreads();

  // LN stats, numpy pairwise, 8 lanes per row (exact np order); rows 0..63
  {
    const int j = tid & 7;
    for (int r = tid >> 3; r < ROWS; r += 32) {
      const float* hrow = &sA[r][0];
      const float mu =
          np_sum256_par8([&](int i) { return hrow[i]; }, j) / 256.0f;
      const float var = np_sum256_par8(
                            [&](int i) {
                              const float d = hrow[i] - mu;
                              return d * d;
                            },
                            j) /
                        256.0f;
      if (j == 0) {
        sMu[r] = mu;
        sRstd[r] = 1.0f / sqrtf(var + 1e-5f);
      }
    }
  }
  __syncthreads();

  // oh = ((h-mu)*rstd)*g + b -> sA (column-parallel, each thread owns col tid)
  {
    const float lg = obj_ln_g[tid], lb = obj_ln_b[tid];
    for (int r = 0; r < ROWS; ++r) {
      const float t = (sA[r][tid] - sMu[r]) * sRstd[r];
      sA[r][tid] = t * lg + lb;
    }
  }
  __syncthreads();

  // obj head GEMM: q = gelu(oh @ ow1 + ob1) -> sA (in place)
#pragma unroll
  for (int i = 0; i < 8; ++i)
#pragma unroll
    for (int j = 0; j < 8; ++j) acc[i][j] = 0.0f;
  gemm_acc8(sA, obj_w1, r0, c0, acc);
  __syncthreads();  // all obj-GEMM reads of sA (oh) complete
  {
#pragma unroll
    for (int j2 = 0; j2 < 8; ++j2) {
      const float b = obj_b1[c0 + j2];
#pragma unroll
      for (int i = 0; i < 8; ++i)
        sA[r0 + i][c0 + j2] = np_geluf(acc[i][j2] + b);
    }
  }
  __syncthreads();

  // logit = (q . ow2) + ob2, sequential ascending fma (np semantics).
  if (tid < ROWS) {
    const int row = tid;
    const float* q = &sA[row][0];
    float L = 0.0f;
    for (int k = 0; k < D; ++k) L = fmaf(q[k], obj_w2[k], L);
    L = L + obj_b2[0];
    g_obj[(size_t)blk * ROWS + row] = np_sigmoidf(L);
  }
}

// ---------------------------------------------------------------------------
// K2: per-batch top-100 via 128-group max tournament. Group g = elements
// {g + 128*j}; init reads are lane-consecutive (conflict-free). Per round:
// wave0 scans 128 group maxima, extracts winner (np tie semantics via packed
// key), zeroes it, recomputes only the winner's group.
// ---------------------------------------------------------------------------
__global__ __launch_bounds__(256) void k2_topk(float* __restrict__ out_scores) {
  const int b = blockIdx.x, tid = threadIdx.x;
  __shared__ ull sKey[TOK_T];
  __shared__ ull sGmax[128];
  __shared__ int sWin;
  for (int i = tid; i < TOK_T; i += 256) {
    const float s = g_obj[b * TOK_T + i];
    sKey[i] = ((ull)__float_as_uint(s) << 32) | (unsigned)(TOK_T - 1 - i);
  }
  __syncthreads();
  // init group maxima: thread t<128 scans its strided group (lane-consecutive)
  if (tid < 128) {
    ull m = 0ull;
    for (int j = 0; j < 64; ++j) {
      const ull v = sKey[tid + 128 * j];
      m = v > m ? v : m;
    }
    sGmax[tid] = m;
  }
  __syncthreads();
  for (int r = 0; r < KSEL; ++r) {
    if (tid < 64) {
      ull m = sGmax[tid];
      const ull o = sGmax[64 + tid];
      if (o > m) m = o;
#pragma unroll
      for (int off = 32; off > 0; off >>= 1) {
        const ull o2 = __shfl_down(m, off, 64);
        if (o2 > m) m = o2;
      }
      if (tid == 0) {
        const int idx = (TOK_T - 1) - (int)(unsigned)(m & 0xFFFFFFFFull);
        out_scores[b * KSEL + r] = __uint_as_float((unsigned)(m >> 32));
        g_sel[b * KSEL + r] = idx;
        sKey[idx] = 0ull;
        sWin = idx & 127;
      }
    }
    __syncthreads();
    if (tid < 64) {
      const int g = sWin;
      ull v = sKey[g + 128 * tid];
#pragma unroll
      for (int off = 32; off > 0; off >>= 1) {
        const ull o = __shfl_down(v, off, 64);
        if (o > v) v = o;
      }
      if (tid == 0) sGmax[g] = v;
    }
    __syncthreads();
  }
}

// ---------------------------------------------------------------------------
// K3: box head + text scores for the 1600 selected tokens, np-f32 semantics.
// 8 tokens/block, 256 threads (thread = output column); stats 8 lanes/row.
// ---------------------------------------------------------------------------
__global__ __launch_bounds__(256) void k3_box(
    const float* __restrict__ vision, const float* __restrict__ fuse_w1,
    const float* __restrict__ fuse_b1, const float* __restrict__ fuse_w2,
    const float* __restrict__ fuse_b2, const float* __restrict__ box_ln_g,
    const float* __restrict__ box_ln_b, const float* __restrict__ box_w1,
    const float* __restrict__ box_b1, const float* __restrict__ box_w2,
    const float* __restrict__ box_b2, float* __restrict__ out) {
#pragma clang fp contract(off)
  const int tid = threadIdx.x, c = tid;
  __shared__ float sV[8][PD];    // vision -> q(box)
  __shared__ float sG[8][PD];    // gelu1 -> bh
  __shared__ float sH[8][PD];    // h
  __shared__ float sTx[8][PD];   // per-token txt row
  __shared__ float sMu[8], sRstd[8];
  __shared__ int sIdx[8], sBat[8];
  if (tid < 8) {
    const int e = blockIdx.x * 8 + tid;
    sBat[tid] = e / KSEL;
    sIdx[tid] = g_sel[e];
  }
  __syncthreads();
  {
    const int u = tid >> 5, col = (tid & 31) * 8;
    const float* src = vision + ((size_t)sBat[u] * TOK_T + sIdx[u]) * D + col;
    *(float4*)&sV[u][col] = *(const float4*)src;
    *(float4*)&sV[u][col + 4] = *(const float4*)(src + 4);
    const float* tsrc = &g_txt[sBat[u] * D + col];
    *(float4*)&sTx[u][col] = *(const float4*)tsrc;
    *(float4*)&sTx[u][col + 4] = *(const float4*)(tsrc + 4);
  }
  __syncthreads();

  float acc[8];
#pragma unroll
  for (int u = 0; u < 8; ++u) acc[u] = 0.0f;
  // GEMM1: k = 0..255 vision, then k = 256..511 text (ascending)
  for (int k = 0; k < D; ++k) {
    const float w = fuse_w1[k * D + c];
#pragma unroll
    for (int u = 0; u < 8; ++u) acc[u] = fmaf(sV[u][k], w, acc[u]);
  }
  for (int k = 0; k < D; ++k) {
    const float w = fuse_w1[(D + k) * D + c];
#pragma unroll
    for (int u = 0; u < 8; ++u) acc[u] = fmaf(sTx[u][k], w, acc[u]);
  }
  {
    const float b = fuse_b1[c];
#pragma unroll
    for (int u = 0; u < 8; ++u) sG[u][c] = np_geluf(acc[u] + b);
  }
  __syncthreads();

  // GEMM2 -> h
#pragma unroll
  for (int u = 0; u < 8; ++u) acc[u] = 0.0f;
  for (int k = 0; k < D; ++k) {
    const float w = fuse_w2[k * D + c];
#pragma unroll
    for (int u = 0; u < 8; ++u) acc[u] = fmaf(sG[u][k], w, acc[u]);
  }
  {
    const float b = fuse_b2[c];
#pragma unroll
    for (int u = 0; u < 8; ++u) sH[u][c] = acc[u] + b;
  }
  __syncthreads();

  // per-token stats (np pairwise), 8 lanes per row; rows 0..7 on wave 0/1
  {
    const int u = tid >> 3, j = tid & 7;
    if (u < 8) {
      const float* h = &sH[u][0];
      const float* tx = &sTx[u][0];
      const float mu = np_sum256_par8([&](int i) { return h[i]; }, j) / 256.0f;
      const float var = np_sum256_par8(
                            [&](int i) {
                              const float d = h[i] - mu;
                              return d * d;
                            },
                            j) /
                        256.0f;
      const float q2 = np_sum256_par8([&](int i) { return h[i] * h[i]; }, j);
      const float den = sqrtf(q2 + 1e-12f);
      const float ts =
          np_sum256_par8([&](int i) { return (h[i] / den) * tx[i]; }, j);
      if (j == 0) {
        sMu[u] = mu;
        sRstd[u] = 1.0f / sqrtf(var + 1e-5f);
        out[8000 + blockIdx.x * 8 + u] = ts;
      }
    }
  }
  __syncthreads();

  // bh -> sG
  {
    const float lg = box_ln_g[c], lb = box_ln_b[c];
#pragma unroll
    for (int u = 0; u < 8; ++u) {
      const float t = (sH[u][c] - sMu[u]) * sRstd[u];
      sG[u][c] = t * lg + lb;
    }
  }
  __syncthreads();

  // box GEMM: q = gelu(bh @ bw1 + bb1) -> sV
#pragma unroll
  for (int u = 0; u < 8; ++u) acc[u] = 0.0f;
  for (int k = 0; k < D; ++k) {
    const float w = box_w1[k * D + c];
#pragma unroll
    for (int u = 0; u < 8; ++u) acc[u] = fmaf(sG[u][k], w, acc[u]);
  }
  {
    const float b = box_b1[c];
#pragma unroll
    for (int u = 0; u < 8; ++u) sV[u][c] = np_geluf(acc[u] + b);
  }
  __syncthreads();

  // logits: sequential ascending fma per (token, j), then + b2, sigmoid
  if (tid < 32) {
    const int u = tid >> 2, j = tid & 3;
    const float* q = &sV[u][0];
    float L = 0.0f;
    for (int k = 0; k < D; ++k) L = fmaf(q[k], box_w2[k * 4 + j], L);
    L = L + box_b2[j];
    out[(blockIdx.x * 8 + u) * 4 + j] = np_sigmoidf(L);
  }
}

extern "C" void kernel_launch(void* const* d_in, const int* in_sizes, int n_in,
                              void* d_out, int out_size, void* d_ws,
                              size_t ws_size, hipStream_t stream) {
  const float* vision   = (const float*)d_in[0];
  const float* text_emb = (const float*)d_in[1];
  const float* fuse_w1  = (const float*)d_in[2];
  const float* fuse_b1  = (const float*)d_in[3];
  const float* fuse_w2  = (const float*)d_in[4];
  const float* fuse_b2  = (const float*)d_in[5];
  const float* box_ln_g = (const float*)d_in[6];
  const float* box_ln_b = (const float*)d_in[7];
  const float* box_w1   = (const float*)d_in[8];
  const float* box_b1   = (const float*)d_in[9];
  const float* box_w2   = (const float*)d_in[10];
  const float* box_b2   = (const float*)d_in[11];
  const float* obj_ln_g = (const float*)d_in[12];
  const float* obj_ln_b = (const float*)d_in[13];
  const float* obj_w1   = (const float*)d_in[14];
  const float* obj_b1   = (const float*)d_in[15];
  const float* obj_w2   = (const float*)d_in[16];
  const float* obj_b2   = (const float*)d_in[17];
  float* out = (float*)d_out;

  k0_txt<<<TOK_B, 256, 0, stream>>>(text_emb);
  k1_obj<<<NTOK / ROWS, 256, 0, stream>>>(
      vision, fuse_w1, fuse_b1, fuse_w2, fuse_b2, obj_ln_g, obj_ln_b, obj_w1,
      obj_b1, obj_w2, obj_b2);
  k2_topk<<<TOK_B, 256, 0, stream>>>(out + 6400);
  k3_box<<<(TOK_B * KSEL) / 8, 256, 0, stream>>>(
      vision, fuse_w1, fuse_b1, fuse_w2, fuse_b2, box_ln_g, box_ln_b, box_w1,
      box_b1, box_w2, box_b2, out);
}

// Round 10
// 1283.405 us; speedup vs baseline: 1.4429x; 1.1144x over previous
//
#include <hip/hip_runtime.h>
#include <math.h>

#define D 256
#define PD 260  // padded LDS row: %4==0 (float4-aligned), %32==4 (bank shift)
#define TOK_B 16
#define TOK_T 8192
#define NTOK (TOK_B * TOK_T)
#define KSEL 100
#define ROWS 64  // R13 optimum: 64 tokens/block, 8 rows/thread, 2 blocks/CU

typedef unsigned long long ull;

// ---- scratch in device globals (d_ws untouched) ----
__device__ float g_txt[TOK_B * D];   // normalized text (f32, np semantics)
__device__ float g_obj[NTOK];        // obj sigmoid scores (f32)
__device__ int   g_sel[TOK_B * KSEL];

// ---------------------------------------------------------------------------
// numpy pairwise_sum emulation (serial form, used by K0).
// ---------------------------------------------------------------------------
template <typename F>
__device__ __forceinline__ float np_sum128_f(F f, int base) {
#pragma clang fp contract(off)
  float r0 = f(base + 0), r1 = f(base + 1), r2 = f(base + 2), r3 = f(base + 3);
  float r4 = f(base + 4), r5 = f(base + 5), r6 = f(base + 6), r7 = f(base + 7);
  for (int i = 8; i < 128; i += 8) {
    r0 += f(base + i + 0); r1 += f(base + i + 1);
    r2 += f(base + i + 2); r3 += f(base + i + 3);
    r4 += f(base + i + 4); r5 += f(base + i + 5);
    r6 += f(base + i + 6); r7 += f(base + i + 7);
  }
  return ((r0 + r1) + (r2 + r3)) + ((r4 + r5) + (r6 + r7));
}
template <typename F>
__device__ __forceinline__ float np_sum256_f(F f) {
#pragma clang fp contract(off)
  return np_sum128_f(f, 0) + np_sum128_f(f, 128);
}

// ---------------------------------------------------------------------------
// Parallel np pairwise sum: 8 lanes (j = lane&7) compute numpy accumulator
// r_j of both 128-halves in np order; combine tree via shfl_xor is
// bit-identical to np's ((r0+r1)+(r2+r3))+((r4+r5)+(r6+r7)).
// ---------------------------------------------------------------------------
template <typename F>
__device__ __forceinline__ float np_sum256_par8(F f, int j) {
#pragma clang fp contract(off)
  float s0 = f(j);
  for (int i = 1; i < 16; ++i) s0 += f(8 * i + j);
  float s1 = f(128 + j);
  for (int i = 1; i < 16; ++i) s1 += f(128 + 8 * i + j);
  s0 += __shfl_xor(s0, 1);
  s0 += __shfl_xor(s0, 2);
  s0 += __shfl_xor(s0, 4);
  s1 += __shfl_xor(s1, 1);
  s1 += __shfl_xor(s1, 2);
  s1 += __shfl_xor(s1, 4);
  return s0 + s1;
}

// scipy-style gelu: f32 divide by f32(sqrt2), f64 erf, f32 compose
__device__ __forceinline__ float np_geluf(float x) {
#pragma clang fp contract(off)
  const float t = x / 1.41421356237309504880f;
  const float e = (float)erf((double)t);
  return (0.5f * x) * (1.0f + e);
}
__device__ __forceinline__ float np_sigmoidf(float x) {
#pragma clang fp contract(off)
  return 1.0f / (1.0f + expf(-x));
}

// ---------------------------------------------------------------------------
// K0: txt = text_emb / sqrt(np.sum(text^2) + 1e-12), all f32 np semantics.
// ---------------------------------------------------------------------------
__global__ __launch_bounds__(256) void k0_txt(const float* __restrict__ text_emb) {
#pragma clang fp contract(off)
  const int b = blockIdx.x, tid = threadIdx.x;
  __shared__ float sSq[D];
  __shared__ float sTot;
  const float e = text_emb[b * D + tid];
  sSq[tid] = e * e;
  __syncthreads();
  if (tid == 0) {
    const float* p = sSq;
    sTot = np_sum256_f([&](int i) { return p[i]; });
  }
  __syncthreads();
  g_txt[b * D + tid] = e / sqrtf(sTot + 1e-12f);
}

// ---------------------------------------------------------------------------
// accumulating GEMM microkernel, R13-proven simple form (no pipelining, no
// sched pragmas, no LDS-W — direct L2 W reads + broadcast A from LDS).
// Verdicts from the session's scan: sched_barrier pins regress (R11 spill,
// R16 fence tax), source ping-pong collapses (R9), LDS-W staging convoys
// (R14), 1-wave ILP exposes latency (R15). This form at 64 rows/block is
// the measured optimum: k1 = 1053 us.
// acc[8][8] += S[r0..r0+7][:] @ W[:,c0..c0+7], strictly ascending k, one
// f32 fma chain per C element (bit-exact vs np).
// ---------------------------------------------------------------------------
__device__ __forceinline__ void gemm_acc8(const float (*__restrict__ S)[PD],
                                          const float* __restrict__ W, int r0,
                                          int c0, float acc[8][8]) {
  for (int k = 0; k < D; k += 4) {
    float ar[8][4];
#pragma unroll
    for (int i = 0; i < 8; ++i) {
      const float4 A = *(const float4*)&S[r0 + i][k];
      ar[i][0] = A.x; ar[i][1] = A.y; ar[i][2] = A.z; ar[i][3] = A.w;
    }
#pragma unroll
    for (int kk = 0; kk < 4; ++kk) {
      const float* wr = W + (size_t)(k + kk) * D + c0;
      float4 W0 = *(const float4*)wr;
      float4 W1 = *(const float4*)(wr + 4);
      const float wv[8] = {W0.x, W0.y, W0.z, W0.w, W1.x, W1.y, W1.z, W1.w};
#pragma unroll
      for (int i = 0; i < 8; ++i)
#pragma unroll
        for (int j = 0; j < 8; ++j)
          acc[i][j] = fmaf(ar[i][kk], wv[j], acc[i][j]);
    }
  }
}

// ---------------------------------------------------------------------------
// K1: obj scores for all tokens, bit-exact np-f32 semantics.
// R13 config: 64 tokens/block, 8 rows x 8 cols per thread, 2 blocks/CU.
// W traffic = waves x full-panel; 8192 waves is the constrained optimum
// (LDS residency caps rows/CU at ~153). Per-output arithmetic identical to
// R6 (ascending-k single fma chain).
// ---------------------------------------------------------------------------
__global__ __launch_bounds__(256, 2) void k1_obj(
    const float* __restrict__ vision, const float* __restrict__ fuse_w1,
    const float* __restrict__ fuse_b1, const float* __restrict__ fuse_w2,
    const float* __restrict__ fuse_b2, const float* __restrict__ obj_ln_g,
    const float* __restrict__ obj_ln_b, const float* __restrict__ obj_w1,
    const float* __restrict__ obj_b1, const float* __restrict__ obj_w2,
    const float* __restrict__ obj_b2) {
#pragma clang fp contract(off)
  const int tid = threadIdx.x;
  const int tr = tid >> 5, tc = tid & 31;
  const int r0 = tr << 3, c0 = tc << 3;   // 8 rows x 8 cols per thread
  const int blk = blockIdx.x;
  const int batch = blk >> 7;  // 128 blocks per batch (8192 tokens / 64)

  __shared__ float sA[ROWS][PD];  // vision -> gelu1 -> h -> oh -> q (in-place)
  __shared__ float sTxt[D];
  __shared__ float sMu[ROWS], sRstd[ROWS];

  // stage vision tile + txt row (pad-aware)
  {
    const float* src = vision + (size_t)blk * (ROWS * D);
#pragma unroll
    for (int i = 0; i < 16; ++i) {
      const int e = i * 1024 + tid * 4;
      const int row = e >> 8, col = e & 255;
      *(float4*)&sA[row][col] = *(const float4*)(src + e);
    }
    sTxt[tid] = g_txt[batch * D + tid];
  }
  __syncthreads();

  float acc[8][8];
#pragma unroll
  for (int i = 0; i < 8; ++i)
#pragma unroll
    for (int j = 0; j < 8; ++j) acc[i][j] = 0.0f;

  // GEMM1 part A: vision rows, k = 0..255 (ascending)
  gemm_acc8(sA, fuse_w1, r0, c0, acc);
  // GEMM1 part B: text rows, k = 256..511 (ascending); tv broadcast per k
  for (int k = 0; k < D; ++k) {
    const float tv = sTxt[k];
    const float* wr = fuse_w1 + (size_t)(D + k) * D + c0;
    float4 W0 = *(const float4*)wr;
    float4 W1 = *(const float4*)(wr + 4);
    const float wv[8] = {W0.x, W0.y, W0.z, W0.w, W1.x, W1.y, W1.z, W1.w};
#pragma unroll
    for (int i = 0; i < 8; ++i)
#pragma unroll
      for (int j = 0; j < 8; ++j) acc[i][j] = fmaf(tv, wv[j], acc[i][j]);
  }
  __syncthreads();  // all GEMM1 reads of sA (vision) complete
  // + b1, gelu -> sA (in place)
  {
#pragma unroll
    for (int j2 = 0; j2 < 8; ++j2) {
      const float b = fuse_b1[c0 + j2];
#pragma unroll
      for (int i = 0; i < 8; ++i)
        sA[r0 + i][c0 + j2] = np_geluf(acc[i][j2] + b);
    }
  }
  __syncthreads();

  // GEMM2: h = gelu1 @ w2 + b2 -> sA (in place)
#pragma unroll
  for (int i = 0; i < 8; ++i)
#pragma unroll
    for (int j = 0; j < 8; ++j) acc[i][j] = 0.0f;
  gemm_acc8(sA, fuse_w2, r0, c0, acc);
  __syncthreads();  // all GEMM2 reads of sA (gelu1) complete
  {
#pragma unroll
    for (int j2 = 0; j2 < 8; ++j2) {
      const float b = fuse_b2[c0 + j2];
#pragma unroll
      for (int i = 0; i < 8; ++i) sA[r0 + i][c0 + j2] = acc[i][j2] + b;
    }
  }
  __syncthreads();

  // LN stats, numpy pairwise, 8 lanes per row (exact np order); rows 0..63
  {
    const int j = tid & 7;
    for (int r = tid >> 3; r < ROWS; r += 32) {
      const float* hrow = &sA[r][0];
      const float mu =
          np_sum256_par8([&](int i) { return hrow[i]; }, j) / 256.0f;
      const float var = np_sum256_par8(
                            [&](int i) {
                              const float d = hrow[i] - mu;
                              return d * d;
                            },
                            j) /
                        256.0f;
      if (j == 0) {
        sMu[r] = mu;
        sRstd[r] = 1.0f / sqrtf(var + 1e-5f);
      }
    }
  }
  __syncthreads();

  // oh = ((h-mu)*rstd)*g + b -> sA (column-parallel, each thread owns col tid)
  {
    const float lg = obj_ln_g[tid], lb = obj_ln_b[tid];
    for (int r = 0; r < ROWS; ++r) {
      const float t = (sA[r][tid] - sMu[r]) * sRstd[r];
      sA[r][tid] = t * lg + lb;
    }
  }
  __syncthreads();

  // obj head GEMM: q = gelu(oh @ ow1 + ob1) -> sA (in place)
#pragma unroll
  for (int i = 0; i < 8; ++i)
#pragma unroll
    for (int j = 0; j < 8; ++j) acc[i][j] = 0.0f;
  gemm_acc8(sA, obj_w1, r0, c0, acc);
  __syncthreads();  // all obj-GEMM reads of sA (oh) complete
  {
#pragma unroll
    for (int j2 = 0; j2 < 8; ++j2) {
      const float b = obj_b1[c0 + j2];
#pragma unroll
      for (int i = 0; i < 8; ++i)
        sA[r0 + i][c0 + j2] = np_geluf(acc[i][j2] + b);
    }
  }
  __syncthreads();

  // logit = (q . ow2) + ob2, sequential ascending fma (np semantics).
  if (tid < ROWS) {
    const int row = tid;
    const float* q = &sA[row][0];
    float L = 0.0f;
    for (int k = 0; k < D; ++k) L = fmaf(q[k], obj_w2[k], L);
    L = L + obj_b2[0];
    g_obj[(size_t)blk * ROWS + row] = np_sigmoidf(L);
  }
}

// ---------------------------------------------------------------------------
// K2: per-batch top-100 via 128-group max tournament. Group g = elements
// {g + 128*j}; init reads are lane-consecutive (conflict-free). Per round:
// wave0 scans 128 group maxima, extracts winner (np tie semantics via packed
// key), zeroes it, recomputes only the winner's group.
// ---------------------------------------------------------------------------
__global__ __launch_bounds__(256) void k2_topk(float* __restrict__ out_scores) {
  const int b = blockIdx.x, tid = threadIdx.x;
  __shared__ ull sKey[TOK_T];
  __shared__ ull sGmax[128];
  __shared__ int sWin;
  for (int i = tid; i < TOK_T; i += 256) {
    const float s = g_obj[b * TOK_T + i];
    sKey[i] = ((ull)__float_as_uint(s) << 32) | (unsigned)(TOK_T - 1 - i);
  }
  __syncthreads();
  // init group maxima: thread t<128 scans its strided group (lane-consecutive)
  if (tid < 128) {
    ull m = 0ull;
    for (int j = 0; j < 64; ++j) {
      const ull v = sKey[tid + 128 * j];
      m = v > m ? v : m;
    }
    sGmax[tid] = m;
  }
  __syncthreads();
  for (int r = 0; r < KSEL; ++r) {
    if (tid < 64) {
      ull m = sGmax[tid];
      const ull o = sGmax[64 + tid];
      if (o > m) m = o;
#pragma unroll
      for (int off = 32; off > 0; off >>= 1) {
        const ull o2 = __shfl_down(m, off, 64);
        if (o2 > m) m = o2;
      }
      if (tid == 0) {
        const int idx = (TOK_T - 1) - (int)(unsigned)(m & 0xFFFFFFFFull);
        out_scores[b * KSEL + r] = __uint_as_float((unsigned)(m >> 32));
        g_sel[b * KSEL + r] = idx;
        sKey[idx] = 0ull;
        sWin = idx & 127;
      }
    }
    __syncthreads();
    if (tid < 64) {
      const int g = sWin;
      ull v = sKey[g + 128 * tid];
#pragma unroll
      for (int off = 32; off > 0; off >>= 1) {
        const ull o = __shfl_down(v, off, 64);
        if (o > v) v = o;
      }
      if (tid == 0) sGmax[g] = v;
    }
    __syncthreads();
  }
}

// ---------------------------------------------------------------------------
// K3: box head + text scores for the 1600 selected tokens, np-f32 semantics.
// 8 tokens/block, 256 threads (thread = output column); stats 8 lanes/row.
// ---------------------------------------------------------------------------
__global__ __launch_bounds__(256) void k3_box(
    const float* __restrict__ vision, const float* __restrict__ fuse_w1,
    const float* __restrict__ fuse_b1, const float* __restrict__ fuse_w2,
    const float* __restrict__ fuse_b2, const float* __restrict__ box_ln_g,
    const float* __restrict__ box_ln_b, const float* __restrict__ box_w1,
    const float* __restrict__ box_b1, const float* __restrict__ box_w2,
    const float* __restrict__ box_b2, float* __restrict__ out) {
#pragma clang fp contract(off)
  const int tid = threadIdx.x, c = tid;
  __shared__ float sV[8][PD];    // vision -> q(box)
  __shared__ float sG[8][PD];    // gelu1 -> bh
  __shared__ float sH[8][PD];    // h
  __shared__ float sTx[8][PD];   // per-token txt row
  __shared__ float sMu[8], sRstd[8];
  __shared__ int sIdx[8], sBat[8];
  if (tid < 8) {
    const int e = blockIdx.x * 8 + tid;
    sBat[tid] = e / KSEL;
    sIdx[tid] = g_sel[e];
  }
  __syncthreads();
  {
    const int u = tid >> 5, col = (tid & 31) * 8;
    const float* src = vision + ((size_t)sBat[u] * TOK_T + sIdx[u]) * D + col;
    *(float4*)&sV[u][col] = *(const float4*)src;
    *(float4*)&sV[u][col + 4] = *(const float4*)(src + 4);
    const float* tsrc = &g_txt[sBat[u] * D + col];
    *(float4*)&sTx[u][col] = *(const float4*)tsrc;
    *(float4*)&sTx[u][col + 4] = *(const float4*)(tsrc + 4);
  }
  __syncthreads();

  float acc[8];
#pragma unroll
  for (int u = 0; u < 8; ++u) acc[u] = 0.0f;
  // GEMM1: k = 0..255 vision, then k = 256..511 text (ascending)
  for (int k = 0; k < D; ++k) {
    const float w = fuse_w1[k * D + c];
#pragma unroll
    for (int u = 0; u < 8; ++u) acc[u] = fmaf(sV[u][k], w, acc[u]);
  }
  for (int k = 0; k < D; ++k) {
    const float w = fuse_w1[(D + k) * D + c];
#pragma unroll
    for (int u = 0; u < 8; ++u) acc[u] = fmaf(sTx[u][k], w, acc[u]);
  }
  {
    const float b = fuse_b1[c];
#pragma unroll
    for (int u = 0; u < 8; ++u) sG[u][c] = np_geluf(acc[u] + b);
  }
  __syncthreads();

  // GEMM2 -> h
#pragma unroll
  for (int u = 0; u < 8; ++u) acc[u] = 0.0f;
  for (int k = 0; k < D; ++k) {
    const float w = fuse_w2[k * D + c];
#pragma unroll
    for (int u = 0; u < 8; ++u) acc[u] = fmaf(sG[u][k], w, acc[u]);
  }
  {
    const float b = fuse_b2[c];
#pragma unroll
    for (int u = 0; u < 8; ++u) sH[u][c] = acc[u] + b;
  }
  __syncthreads();

  // per-token stats (np pairwise), 8 lanes per row; rows 0..7 on wave 0/1
  {
    const int u = tid >> 3, j = tid & 7;
    if (u < 8) {
      const float* h = &sH[u][0];
      const float* tx = &sTx[u][0];
      const float mu = np_sum256_par8([&](int i) { return h[i]; }, j) / 256.0f;
      const float var = np_sum256_par8(
                            [&](int i) {
                              const float d = h[i] - mu;
                              return d * d;
                            },
                            j) /
                        256.0f;
      const float q2 = np_sum256_par8([&](int i) { return h[i] * h[i]; }, j);
      const float den = sqrtf(q2 + 1e-12f);
      const float ts =
          np_sum256_par8([&](int i) { return (h[i] / den) * tx[i]; }, j);
      if (j == 0) {
        sMu[u] = mu;
        sRstd[u] = 1.0f / sqrtf(var + 1e-5f);
        out[8000 + blockIdx.x * 8 + u] = ts;
      }
    }
  }
  __syncthreads();

  // bh -> sG
  {
    const float lg = box_ln_g[c], lb = box_ln_b[c];
#pragma unroll
    for (int u = 0; u < 8; ++u) {
      const float t = (sH[u][c] - sMu[u]) * sRstd[u];
      sG[u][c] = t * lg + lb;
    }
  }
  __syncthreads();

  // box GEMM: q = gelu(bh @ bw1 + bb1) -> sV
#pragma unroll
  for (int u = 0; u < 8; ++u) acc[u] = 0.0f;
  for (int k = 0; k < D; ++k) {
    const float w = box_w1[k * D + c];
#pragma unroll
    for (int u = 0; u < 8; ++u) acc[u] = fmaf(sG[u][k], w, acc[u]);
  }
  {
    const float b = box_b1[c];
#pragma unroll
    for (int u = 0; u < 8; ++u) sV[u][c] = np_geluf(acc[u] + b);
  }
  __syncthreads();

  // logits: sequential ascending fma per (token, j), then + b2, sigmoid
  if (tid < 32) {
    const int u = tid >> 2, j = tid & 3;
    const float* q = &sV[u][0];
    float L = 0.0f;
    for (int k = 0; k < D; ++k) L = fmaf(q[k], box_w2[k * 4 + j], L);
    L = L + box_b2[j];
    out[(blockIdx.x * 8 + u) * 4 + j] = np_sigmoidf(L);
  }
}

extern "C" void kernel_launch(void* const* d_in, const int* in_sizes, int n_in,
                              void* d_out, int out_size, void* d_ws,
                              size_t ws_size, hipStream_t stream) {
  const float* vision   = (const float*)d_in[0];
  const float* text_emb = (const float*)d_in[1];
  const float* fuse_w1  = (const float*)d_in[2];
  const float* fuse_b1  = (const float*)d_in[3];
  const float* fuse_w2  = (const float*)d_in[4];
  const float* fuse_b2  = (const float*)d_in[5];
  const float* box_ln_g = (const float*)d_in[6];
  const float* box_ln_b = (const float*)d_in[7];
  const float* box_w1   = (const float*)d_in[8];
  const float* box_b1   = (const float*)d_in[9];
  const float* box_w2   = (const float*)d_in[10];
  const float* box_b2   = (const float*)d_in[11];
  const float* obj_ln_g = (const float*)d_in[12];
  const float* obj_ln_b = (const float*)d_in[13];
  const float* obj_w1   = (const float*)d_in[14];
  const float* obj_b1   = (const float*)d_in[15];
  const float* obj_w2   = (const float*)d_in[16];
  const float* obj_b2   = (const float*)d_in[17];
  float* out = (float*)d_out;

  k0_txt<<<TOK_B, 256, 0, stream>>>(text_emb);
  k1_obj<<<NTOK / ROWS, 256, 0, stream>>>(
      vision, fuse_w1, fuse_b1, fuse_w2, fuse_b2, obj_ln_g, obj_ln_b, obj_w1,
      obj_b1, obj_w2, obj_b2);
  k2_topk<<<TOK_B, 256, 0, stream>>>(out + 6400);
  k3_box<<<(TOK_B * KSEL) / 8, 256, 0, stream>>>(
      vision, fuse_w1, fuse_b1, fuse_w2, fuse_b2, box_ln_g, box_ln_b, box_w1,
      box_b1, box_w2, box_b2, out);
}